// Round 13
// baseline (360.362 us; speedup 1.0000x reference)
//
#include <hip/hip_runtime.h>

#define M_NODES 20000
#define K_FEATS 3703
#define PADK 3712          // 116*32
#define NH 50
#define NC 6
#define N_EDGES_C 640000
#define NKB 116            // PADK/32 k-blocks

typedef __attribute__((ext_vector_type(8))) __bf16 bf16x8;
typedef __attribute__((ext_vector_type(4))) float f32x4;

// ============ pack W1 -> MFMA B-fragment layout, bf16 hi/lo ============
__global__ void k_packB(const float* __restrict__ W1, unsigned short* __restrict__ Bh,
                        unsigned short* __restrict__ Bl) {
  int idx = blockIdx.x * 256 + threadIdx.x;
  if (idx >= NKB * 4 * 64 * 8) return;
  int j = idx & 7;
  int lane = (idx >> 3) & 63;
  int t = (idx >> 9) & 3;
  int kb = idx >> 11;
  int k = kb * 32 + (lane >> 4) * 8 + j;
  int c = t * 16 + (lane & 15);
  float v = (k < K_FEATS && c < NH) ? W1[k * NH + c] : 0.f;
  __bf16 hb = (__bf16)v;
  float hf = (float)hb;
  __bf16 lb = (__bf16)(v - hf);
  Bh[idx] = *(unsigned short*)&hb;
  Bl[idx] = *(unsigned short*)&lb;
}

// ============ GEMM1 via MFMA bf16x3 — round-13: BM=64, 1 m-tile per wave ============
// Block = 4 waves x 16 rows = 64 rows; grid (313, 8) = 2504 blocks.
// Per-wave: acc 16 VGPR, 2-deep A dbuf 16, B transient 32 -> ~90 VGPR total,
// ~5 waves/SIMD resident (vs ~3 before): more outstanding HBM loads -> closer to BW floor.
__global__ __launch_bounds__(256) void k_gemm1(const float* __restrict__ A,
    const unsigned short* __restrict__ Bph, const unsigned short* __restrict__ Bpl,
    float* __restrict__ part, int KS) {
  const int lane = threadIdx.x & 63;
  const int w = threadIdx.x >> 6;
  const int row0 = blockIdx.x * 64 + w * 16;     // wave's m-tile base
  const int s = blockIdx.y;
  const int ks = s * KS;
  const int ke = (ks + KS < PADK) ? ks + KS : PADK;
  const int nsteps = (ke - ks) >> 5;             // 16 (full) or 4 (last slice) — even
  const int g = lane >> 4;
  const int rl = lane & 15;
  const int r0c = min(row0 + rl, M_NODES - 1);
  const float* a0p = A + (size_t)r0c * K_FEATS + 8 * g;
  const bf16x8* BH = (const bf16x8*)Bph;
  const bf16x8* BL = (const bf16x8*)Bpl;

  f32x4 acc[4];
  #pragma unroll
  for (int t = 0; t < 4; ++t) acc[t] = (f32x4){0.f, 0.f, 0.f, 0.f};

  #define LOADA(d0, k0) {                                         \
    d0[0] = *(const float4*)(a0p + (k0));                         \
    d0[1] = *(const float4*)(a0p + (k0) + 4); }
  #define LOADAG(d0, k0) {                                        \
    _Pragma("unroll") for (int j = 0; j < 8; ++j) {               \
      int gk = (k0) + 8 * g + j;                                  \
      ((float*)d0)[j] = (gk < K_FEATS) ? a0p[(k0) + j] : 0.f; } }
  #define LDSEL(d0, k0) {                                         \
    if ((k0) + 32 > K_FEATS) { LOADAG(d0, k0) }                   \
    else { LOADA(d0, k0) } }

  #define BODY(sa, k0) {                                          \
    const int kb4 = ((k0) >> 5) * 4;                              \
    bf16x8 bh0 = BH[(kb4 + 0) * 64 + lane];                       \
    bf16x8 bh1 = BH[(kb4 + 1) * 64 + lane];                       \
    bf16x8 bh2 = BH[(kb4 + 2) * 64 + lane];                       \
    bf16x8 bh3 = BH[(kb4 + 3) * 64 + lane];                       \
    bf16x8 bl0 = BL[(kb4 + 0) * 64 + lane];                       \
    bf16x8 bl1 = BL[(kb4 + 1) * 64 + lane];                       \
    bf16x8 bl2 = BL[(kb4 + 2) * 64 + lane];                       \
    bf16x8 bl3 = BL[(kb4 + 3) * 64 + lane];                       \
    bf16x8 ah, al;                                                \
    _Pragma("unroll") for (int j = 0; j < 8; ++j) {               \
      float xv = ((const float*)sa)[j];                           \
      __bf16 hb = (__bf16)xv; float hf = (float)hb;               \
      ah[j] = hb; al[j] = (__bf16)(xv - hf);                      \
    }                                                             \
    acc[0] = __builtin_amdgcn_mfma_f32_16x16x32_bf16(ah, bh0, acc[0], 0, 0, 0); \
    acc[1] = __builtin_amdgcn_mfma_f32_16x16x32_bf16(ah, bh1, acc[1], 0, 0, 0); \
    acc[2] = __builtin_amdgcn_mfma_f32_16x16x32_bf16(ah, bh2, acc[2], 0, 0, 0); \
    acc[3] = __builtin_amdgcn_mfma_f32_16x16x32_bf16(ah, bh3, acc[3], 0, 0, 0); \
    acc[0] = __builtin_amdgcn_mfma_f32_16x16x32_bf16(al, bh0, acc[0], 0, 0, 0); \
    acc[1] = __builtin_amdgcn_mfma_f32_16x16x32_bf16(al, bh1, acc[1], 0, 0, 0); \
    acc[2] = __builtin_amdgcn_mfma_f32_16x16x32_bf16(al, bh2, acc[2], 0, 0, 0); \
    acc[3] = __builtin_amdgcn_mfma_f32_16x16x32_bf16(al, bh3, acc[3], 0, 0, 0); \
    acc[0] = __builtin_amdgcn_mfma_f32_16x16x32_bf16(ah, bl0, acc[0], 0, 0, 0); \
    acc[1] = __builtin_amdgcn_mfma_f32_16x16x32_bf16(ah, bl1, acc[1], 0, 0, 0); \
    acc[2] = __builtin_amdgcn_mfma_f32_16x16x32_bf16(ah, bl2, acc[2], 0, 0, 0); \
    acc[3] = __builtin_amdgcn_mfma_f32_16x16x32_bf16(ah, bl3, acc[3], 0, 0, 0); }

  float4 xa[2], ya[2];
  LOADA(xa, ks);                               // step 0 never tail-guarded
  for (int t2 = 0; t2 < nsteps; t2 += 2) {
    const int k0 = ks + (t2 << 5);
    const int k1 = k0 + 32;
    LDSEL(ya, k1);
    BODY(xa, k0);
    if (t2 + 2 < nsteps) {
      LDSEL(xa, k0 + 64);
    }
    BODY(ya, k1);
  }
  #undef LOADA
  #undef LOADAG
  #undef LDSEL
  #undef BODY

  // C/D layout: col = t2*16 + (lane&15), row = row0 + (lane>>4)*4 + q
  float* p = part + (size_t)s * 1000000;
  #pragma unroll
  for (int t2 = 0; t2 < 4; ++t2) {
    int col = t2 * 16 + rl;
    if (col < NH) {
      int rowb = row0 + g * 4;
      f32x4 v = acc[t2];
      #pragma unroll
      for (int q = 0; q < 4; ++q) {
        int row = rowb + q;
        if (row < M_NODES) p[row * NH + col] = v[q];
      }
    }
  }
}

// ============ epilogue: x1 = relu(sum_s part[s] + b1) ============
__global__ void k_epi(const float* __restrict__ part, const float* __restrict__ b1,
                      float* __restrict__ x1, int S) {
  int i = blockIdx.x * 256 + threadIdx.x;
  if (i >= M_NODES * NH) return;
  float v = b1[i % NH];
  for (int s = 0; s < S; ++s) v += part[(size_t)s * 1000000 + i];
  x1[i] = fmaxf(v, 0.f);
}

// ============ fused MLP layers 2..4 ============
__global__ __launch_bounds__(256) void k_mlp(const float* __restrict__ x1,
    const float* __restrict__ W2, const float* __restrict__ b2,
    const float* __restrict__ W3, const float* __restrict__ b3,
    const float* __restrict__ W4, const float* __restrict__ b4,
    float* __restrict__ z) {
  __shared__ float lX[32 * 51];
  __shared__ float lW2[50 * 52];
  __shared__ float lW3[50 * 52];
  __shared__ float lW4[50 * 8];
  const int tid = threadIdx.x;
  const int row0 = blockIdx.x * 32;
  for (int idx = tid; idx < 2500; idx += 256) {
    int k = idx / 50, n = idx % 50;
    lW2[k * 52 + n] = W2[idx];
    lW3[k * 52 + n] = W3[idx];
  }
  for (int idx = tid; idx < 300; idx += 256) {
    int k = idx / 6, n = idx % 6;
    lW4[k * 8 + n] = W4[idx];
  }
  for (int idx = tid; idx < 1600; idx += 256) {
    int r = idx / 50, k = idx % 50;
    int gr = row0 + r;
    lX[r * 51 + k] = (gr < M_NODES) ? x1[gr * 50 + k] : 0.f;
  }
  __syncthreads();
  const int r = tid >> 3, cg = tid & 7;
  float x[50];
  #pragma unroll
  for (int k = 0; k < 50; ++k) x[k] = lX[r * 51 + k];

  for (int layer = 0; layer < 2; ++layer) {
    const float* lW = (layer == 0) ? lW2 : lW3;
    const float* bg = (layer == 0) ? b2 : b3;
    float acc[7];
    #pragma unroll
    for (int j = 0; j < 7; ++j) {
      int n = cg + 8 * j;
      acc[j] = (n < 50) ? bg[n] : 0.f;
    }
    #pragma unroll
    for (int k = 0; k < 50; ++k) {
      float xk = x[k];
      #pragma unroll
      for (int j = 0; j < 7; ++j) {
        int n = cg + 8 * j;
        if (n < 50) acc[j] = fmaf(xk, lW[k * 52 + n], acc[j]);
      }
    }
    __syncthreads();
    #pragma unroll
    for (int j = 0; j < 7; ++j) {
      int n = cg + 8 * j;
      if (n < 50) lX[r * 51 + n] = fmaxf(acc[j], 0.f);
    }
    __syncthreads();
    #pragma unroll
    for (int k = 0; k < 50; ++k) x[k] = lX[r * 51 + k];
  }
  if (cg < 6) {
    float accz = b4[cg];
    #pragma unroll
    for (int k = 0; k < 50; ++k) accz = fmaf(x[k], lW4[k * 8 + cg], accz);
    int gr = row0 + r;
    if (gr < M_NODES) z[gr * 6 + cg] = accz;
  }
}

// ============ CSR incidence build ============
__global__ void k_count(const int* __restrict__ sx, const int* __restrict__ sy,
                        int* __restrict__ cnt) {
  int e = blockIdx.x * 256 + threadIdx.x;
  if (e >= N_EDGES_C) return;
  atomicAdd(&cnt[sx[e]], 1);
  atomicAdd(&cnt[sy[e]], 1);
}

__global__ __launch_bounds__(1024) void k_scan(const int* __restrict__ cnt,
                                               int* __restrict__ off,
                                               int* __restrict__ cur) {
  __shared__ int sums[1024];
  int t = threadIdx.x;
  int base = t * 20;
  int local[20];
  int s = 0;
  #pragma unroll
  for (int j = 0; j < 20; ++j) {
    int idx = base + j;
    int v = (idx < M_NODES) ? cnt[idx] : 0;
    local[j] = s;
    s += v;
  }
  sums[t] = s;
  __syncthreads();
  for (int d = 1; d < 1024; d <<= 1) {
    int v = (t >= d) ? sums[t - d] : 0;
    __syncthreads();
    sums[t] += v;
    __syncthreads();
  }
  int excl = sums[t] - s;
  #pragma unroll
  for (int j = 0; j < 20; ++j) {
    int idx = base + j;
    if (idx < M_NODES) {
      int o = excl + local[j];
      off[idx] = o;
      cur[idx] = o;
    }
  }
  if (t == 1023) off[M_NODES] = sums[1023];
}

// packed entry: {partner<<1 | side, rel_bits}
__global__ void k_scatter(const int* __restrict__ sx, const int* __restrict__ sy,
                          const float* __restrict__ rel,
                          int* __restrict__ cur, int2* __restrict__ ent) {
  int e = blockIdx.x * 256 + threadIdx.x;
  if (e >= N_EDGES_C) return;
  int a = sx[e], b = sy[e];
  int rb = __float_as_int(rel[e]);
  int p = atomicAdd(&cur[a], 1);
  ent[p] = make_int2((b << 1), rb);       // node a is x-side (side 0)
  int q = atomicAdd(&cur[b], 1);
  ent[q] = make_int2((a << 1) | 1, rb);   // node b is y-side (side 1)
}

// ============ KENN gather + in-wave combine (+ optional softmax) — r12-proven ============
__global__ __launch_bounds__(256) void k_gather(const float* __restrict__ z,
    const int* __restrict__ off, const int2* __restrict__ ent,
    const float* __restrict__ cw, float* __restrict__ zn,
    float* __restrict__ out, int last) {
  int t = blockIdx.x * 256 + threadIdx.x;
  int s = t & 7;
  int n = t >> 3;
  int o0 = off[n];
  int deg = off[n + 1] - o0;
  int lo = o0 + ((deg * s) >> 3);
  int hi = o0 + ((deg * (s + 1)) >> 3);

  const float2* zr = (const float2*)(z + n * 6);
  float2 a0 = zr[0], a1 = zr[1], a2 = zr[2];
  float znv[6] = {a0.x, a0.y, a1.x, a1.y, a2.x, a2.y};
  float w[6];
  #pragma unroll
  for (int c = 0; c < 6; ++c) w[c] = cw[c];
  float en_neg[6], en_pos[6];
  #pragma unroll
  for (int c = 0; c < 6; ++c) {
    en_neg[c] = __expf(-znv[c]);
    en_pos[c] = __expf(znv[c]);
  }
  float dz[6] = {0.f, 0.f, 0.f, 0.f, 0.f, 0.f};

  for (int i = lo; i < hi; ++i) {
    int2 e2 = ent[i];
    int partner = e2.x >> 1;
    int side = e2.x & 1;
    float r = __int_as_float(e2.y);
    const float2* zp2 = (const float2*)(z + partner * 6);
    float2 p0 = zp2[0], p1 = zp2[1], p2 = zp2[2];
    float zpv[6] = {p0.x, p0.y, p1.x, p1.y, p2.x, p2.y};
    float e2v = __expf(-r);
    #pragma unroll
    for (int c = 0; c < 6; ++c) {
      float e0 = side ? __expf(-zpv[c]) : en_neg[c];
      float e1 = side ? en_pos[c] : __expf(zpv[c]);
      float inv = w[c] / (e0 + e1 + e2v);
      dz[c] += (side ? e1 : -e0) * inv;
    }
  }

  #pragma unroll
  for (int c = 0; c < 6; ++c) {
    float v = dz[c];
    v += __shfl_xor(v, 1, 8);
    v += __shfl_xor(v, 2, 8);
    v += __shfl_xor(v, 4, 8);
    dz[c] = v;
  }

  if (s == 0) {
    float v[6];
    #pragma unroll
    for (int c = 0; c < 6; ++c) v[c] = znv[c] + dz[c];
    if (!last) {
      float2* o2 = (float2*)(zn + n * 6);
      o2[0] = make_float2(v[0], v[1]);
      o2[1] = make_float2(v[2], v[3]);
      o2[2] = make_float2(v[4], v[5]);
    } else {
      float m = v[0];
      #pragma unroll
      for (int c = 1; c < 6; ++c) m = fmaxf(m, v[c]);
      float sum = 0.f, ev[6];
      #pragma unroll
      for (int c = 0; c < 6; ++c) { ev[c] = __expf(v[c] - m); sum += ev[c]; }
      float inv = 1.f / sum;
      float2* o2 = (float2*)(out + n * 6);
      o2[0] = make_float2(ev[0] * inv, ev[1] * inv);
      o2[1] = make_float2(ev[2] * inv, ev[3] * inv);
      o2[2] = make_float2(ev[4] * inv, ev[5] * inv);
    }
  }
}

extern "C" void kernel_launch(void* const* d_in, const int* in_sizes, int n_in,
                              void* d_out, int out_size, void* d_ws, size_t ws_size,
                              hipStream_t stream) {
  const float* A   = (const float*)d_in[0];
  const float* rel = (const float*)d_in[1];
  const int*   sx  = (const int*)d_in[2];
  const int*   sy  = (const int*)d_in[3];
  const float* W1  = (const float*)d_in[4];
  const float* b1  = (const float*)d_in[5];
  const float* W2  = (const float*)d_in[6];
  const float* b2  = (const float*)d_in[7];
  const float* W3  = (const float*)d_in[8];
  const float* b3  = (const float*)d_in[9];
  const float* W4  = (const float*)d_in[10];
  const float* b4  = (const float*)d_in[11];
  const float* cw  = (const float*)d_in[12];

  const int S = 8, KS = 512;    // grid (313, 8) = 2504 blocks, BM=64

  float* base = (float*)d_ws;
  float* part = base;                         // 8M floats (dead after k_epi; CSR aliases)
  float* x1   = base + 8000000;               // 1M
  float* zA   = base + 9000000;               // 120000
  float* zB   = base + 9120000;               // 120000
  unsigned short* Bph = (unsigned short*)(base + 9240000);   // 237568 ushorts
  unsigned short* Bpl = (unsigned short*)(base + 9360000);   // 237568 ushorts

  // CSR arrays alias the part region (dead after k_epi)
  int*  cnt  = (int*)base;                    // 20001
  int*  off  = (int*)base + 24576;            // 20001
  int*  cur  = (int*)base + 49152;            // 20001
  int2* ent  = (int2*)((int*)base + 73728);   // 1.28M int2 -> ends 2,633,728 ints

  k_packB<<<(NKB * 4 * 64 * 8 + 255) / 256, 256, 0, stream>>>(W1, Bph, Bpl);
  k_gemm1<<<dim3(313, S), 256, 0, stream>>>(A, Bph, Bpl, part, KS);
  k_epi<<<(M_NODES * NH + 255) / 256, 256, 0, stream>>>(part, b1, x1, S);
  k_mlp<<<(M_NODES + 31) / 32, 256, 0, stream>>>(x1, W2, b2, W3, b3, W4, b4, zA);

  hipMemsetAsync(cnt, 0, (M_NODES + 1) * sizeof(int), stream);
  k_count<<<(N_EDGES_C + 255) / 256, 256, 0, stream>>>(sx, sy, cnt);
  k_scan<<<1, 1024, 0, stream>>>(cnt, off, cur);
  k_scatter<<<(N_EDGES_C + 255) / 256, 256, 0, stream>>>(sx, sy, rel, cur, ent);

  float* zc = zA;
  float* zn = zB;
  for (int l = 0; l < 3; ++l) {
    k_gather<<<M_NODES * 8 / 256, 256, 0, stream>>>(
        zc, off, ent, cw + 6 * l, zn, (float*)d_out, (l == 2) ? 1 : 0);
    float* t = zc; zc = zn; zn = t;
  }
}

// Round 14
// 345.123 us; speedup vs baseline: 1.0442x; 1.0442x over previous
//
#include <hip/hip_runtime.h>

#define M_NODES 20000
#define K_FEATS 3703
#define PADK 3712          // 116*32
#define NH 50
#define NC 6
#define N_EDGES_C 640000
#define NKB 116            // PADK/32 k-blocks

typedef __attribute__((ext_vector_type(8))) __bf16 bf16x8;
typedef __attribute__((ext_vector_type(4))) float f32x4;

// ============ pack W1 -> MFMA B-fragment layout, bf16 hi/lo ============
__global__ void k_packB(const float* __restrict__ W1, unsigned short* __restrict__ Bh,
                        unsigned short* __restrict__ Bl) {
  int idx = blockIdx.x * 256 + threadIdx.x;
  if (idx >= NKB * 4 * 64 * 8) return;
  int j = idx & 7;
  int lane = (idx >> 3) & 63;
  int t = (idx >> 9) & 3;
  int kb = idx >> 11;
  int k = kb * 32 + (lane >> 4) * 8 + j;
  int c = t * 16 + (lane & 15);
  float v = (k < K_FEATS && c < NH) ? W1[k * NH + c] : 0.f;
  __bf16 hb = (__bf16)v;
  float hf = (float)hb;
  __bf16 lb = (__bf16)(v - hf);
  Bh[idx] = *(unsigned short*)&hb;
  Bl[idx] = *(unsigned short*)&lb;
}

// ============ GEMM1 via MFMA bf16x3 (r12-proven: BM=128, 3-deep rotating A pipeline) ============
__global__ __launch_bounds__(256) void k_gemm1(const float* __restrict__ A,
    const unsigned short* __restrict__ Bph, const unsigned short* __restrict__ Bpl,
    float* __restrict__ part, int KS) {
  const int lane = threadIdx.x & 63;
  const int w = threadIdx.x >> 6;
  const int row0 = blockIdx.x * 128 + w * 32;
  const int s = blockIdx.y;
  const int ks = s * KS;
  const int ke = (ks + KS < PADK) ? ks + KS : PADK;
  const int nsteps = (ke - ks) >> 5;
  const int g = lane >> 4;
  const int rl = lane & 15;
  const int r0c = min(row0 + rl, M_NODES - 1);
  const int r1c = min(row0 + 16 + rl, M_NODES - 1);
  const float* a0p = A + (size_t)r0c * K_FEATS + 8 * g;
  const float* a1p = A + (size_t)r1c * K_FEATS + 8 * g;
  const bf16x8* BH = (const bf16x8*)Bph;
  const bf16x8* BL = (const bf16x8*)Bpl;

  f32x4 acc[2][4];
  #pragma unroll
  for (int i = 0; i < 2; ++i)
    #pragma unroll
    for (int t = 0; t < 4; ++t) acc[i][t] = (f32x4){0.f, 0.f, 0.f, 0.f};

  #define LOADA(d0, d1, k0) {                                     \
    d0[0] = *(const float4*)(a0p + (k0));                         \
    d0[1] = *(const float4*)(a0p + (k0) + 4);                     \
    d1[0] = *(const float4*)(a1p + (k0));                         \
    d1[1] = *(const float4*)(a1p + (k0) + 4); }
  #define LOADAG(d0, d1, k0) {                                    \
    _Pragma("unroll") for (int j = 0; j < 8; ++j) {               \
      int gk = (k0) + 8 * g + j;                                  \
      float v0 = (gk < K_FEATS) ? a0p[(k0) + j] : 0.f;            \
      float v1 = (gk < K_FEATS) ? a1p[(k0) + j] : 0.f;            \
      ((float*)d0)[j] = v0; ((float*)d1)[j] = v1; } }
  #define LDSEL(d0, d1, k0) {                                     \
    if ((k0) + 32 > K_FEATS) { LOADAG(d0, d1, k0) }               \
    else { LOADA(d0, d1, k0) } }

  #define BODY(sa0, sa1, k0) {                                    \
    const int kb4 = ((k0) >> 5) * 4;                              \
    bf16x8 bh0 = BH[(kb4 + 0) * 64 + lane];                       \
    bf16x8 bh1 = BH[(kb4 + 1) * 64 + lane];                       \
    bf16x8 bh2 = BH[(kb4 + 2) * 64 + lane];                       \
    bf16x8 bh3 = BH[(kb4 + 3) * 64 + lane];                       \
    bf16x8 bl0 = BL[(kb4 + 0) * 64 + lane];                       \
    bf16x8 bl1 = BL[(kb4 + 1) * 64 + lane];                       \
    bf16x8 bl2 = BL[(kb4 + 2) * 64 + lane];                       \
    bf16x8 bl3 = BL[(kb4 + 3) * 64 + lane];                       \
    bf16x8 ah0, al0, ah1, al1;                                    \
    _Pragma("unroll") for (int j = 0; j < 8; ++j) {               \
      float xv = ((const float*)sa0)[j];                          \
      __bf16 hb = (__bf16)xv; float hf = (float)hb;               \
      ah0[j] = hb; al0[j] = (__bf16)(xv - hf);                    \
      float yv = ((const float*)sa1)[j];                          \
      __bf16 hb2 = (__bf16)yv; float hf2 = (float)hb2;            \
      ah1[j] = hb2; al1[j] = (__bf16)(yv - hf2);                  \
    }                                                             \
    acc[0][0] = __builtin_amdgcn_mfma_f32_16x16x32_bf16(ah0, bh0, acc[0][0], 0, 0, 0); \
    acc[0][1] = __builtin_amdgcn_mfma_f32_16x16x32_bf16(ah0, bh1, acc[0][1], 0, 0, 0); \
    acc[0][2] = __builtin_amdgcn_mfma_f32_16x16x32_bf16(ah0, bh2, acc[0][2], 0, 0, 0); \
    acc[0][3] = __builtin_amdgcn_mfma_f32_16x16x32_bf16(ah0, bh3, acc[0][3], 0, 0, 0); \
    acc[1][0] = __builtin_amdgcn_mfma_f32_16x16x32_bf16(ah1, bh0, acc[1][0], 0, 0, 0); \
    acc[1][1] = __builtin_amdgcn_mfma_f32_16x16x32_bf16(ah1, bh1, acc[1][1], 0, 0, 0); \
    acc[1][2] = __builtin_amdgcn_mfma_f32_16x16x32_bf16(ah1, bh2, acc[1][2], 0, 0, 0); \
    acc[1][3] = __builtin_amdgcn_mfma_f32_16x16x32_bf16(ah1, bh3, acc[1][3], 0, 0, 0); \
    acc[0][0] = __builtin_amdgcn_mfma_f32_16x16x32_bf16(al0, bh0, acc[0][0], 0, 0, 0); \
    acc[0][1] = __builtin_amdgcn_mfma_f32_16x16x32_bf16(al0, bh1, acc[0][1], 0, 0, 0); \
    acc[0][2] = __builtin_amdgcn_mfma_f32_16x16x32_bf16(al0, bh2, acc[0][2], 0, 0, 0); \
    acc[0][3] = __builtin_amdgcn_mfma_f32_16x16x32_bf16(al0, bh3, acc[0][3], 0, 0, 0); \
    acc[1][0] = __builtin_amdgcn_mfma_f32_16x16x32_bf16(al1, bh0, acc[1][0], 0, 0, 0); \
    acc[1][1] = __builtin_amdgcn_mfma_f32_16x16x32_bf16(al1, bh1, acc[1][1], 0, 0, 0); \
    acc[1][2] = __builtin_amdgcn_mfma_f32_16x16x32_bf16(al1, bh2, acc[1][2], 0, 0, 0); \
    acc[1][3] = __builtin_amdgcn_mfma_f32_16x16x32_bf16(al1, bh3, acc[1][3], 0, 0, 0); \
    acc[0][0] = __builtin_amdgcn_mfma_f32_16x16x32_bf16(ah0, bl0, acc[0][0], 0, 0, 0); \
    acc[0][1] = __builtin_amdgcn_mfma_f32_16x16x32_bf16(ah0, bl1, acc[0][1], 0, 0, 0); \
    acc[0][2] = __builtin_amdgcn_mfma_f32_16x16x32_bf16(ah0, bl2, acc[0][2], 0, 0, 0); \
    acc[0][3] = __builtin_amdgcn_mfma_f32_16x16x32_bf16(ah0, bl3, acc[0][3], 0, 0, 0); \
    acc[1][0] = __builtin_amdgcn_mfma_f32_16x16x32_bf16(ah1, bl0, acc[1][0], 0, 0, 0); \
    acc[1][1] = __builtin_amdgcn_mfma_f32_16x16x32_bf16(ah1, bl1, acc[1][1], 0, 0, 0); \
    acc[1][2] = __builtin_amdgcn_mfma_f32_16x16x32_bf16(ah1, bl2, acc[1][2], 0, 0, 0); \
    acc[1][3] = __builtin_amdgcn_mfma_f32_16x16x32_bf16(ah1, bl3, acc[1][3], 0, 0, 0); }

  float4 p0a[2], p0b[2], p1a[2], p1b[2], p2a[2], p2b[2];
  LDSEL(p0a, p0b, ks);
  if (nsteps > 1) LDSEL(p1a, p1b, ks + 32);
  if (nsteps > 2) LDSEL(p2a, p2b, ks + 64);

  int t = 0;
  for (; t + 3 <= nsteps; t += 3) {
    const int k0 = ks + (t << 5);
    BODY(p0a, p0b, k0);
    if (t + 3 < nsteps) LDSEL(p0a, p0b, k0 + 96);
    BODY(p1a, p1b, k0 + 32);
    if (t + 4 < nsteps) LDSEL(p1a, p1b, k0 + 128);
    BODY(p2a, p2b, k0 + 64);
    if (t + 5 < nsteps) LDSEL(p2a, p2b, k0 + 160);
  }
  if (t < nsteps)     BODY(p0a, p0b, ks + (t << 5));
  if (t + 1 < nsteps) BODY(p1a, p1b, ks + ((t + 1) << 5));
  #undef LOADA
  #undef LOADAG
  #undef LDSEL
  #undef BODY

  // C/D layout: col = lane&15, row = (lane>>4)*4 + reg
  float* p = part + (size_t)s * 1000000;
  #pragma unroll
  for (int i = 0; i < 2; ++i) {
    #pragma unroll
    for (int t2 = 0; t2 < 4; ++t2) {
      int col = t2 * 16 + rl;
      if (col < NH) {
        int rowb = row0 + i * 16 + g * 4;
        f32x4 v = acc[i][t2];
        #pragma unroll
        for (int q = 0; q < 4; ++q) {
          int row = rowb + q;
          if (row < M_NODES) p[row * NH + col] = v[q];
        }
      }
    }
  }
}

// ============ epilogue: x1 = relu(sum_s part[s] + b1) ============
__global__ void k_epi(const float* __restrict__ part, const float* __restrict__ b1,
                      float* __restrict__ x1, int S) {
  int i = blockIdx.x * 256 + threadIdx.x;
  if (i >= M_NODES * NH) return;
  float v = b1[i % NH];
  for (int s = 0; s < S; ++s) v += part[(size_t)s * 1000000 + i];
  x1[i] = fmaxf(v, 0.f);
}

// ============ fused MLP layers 2..4 ============
__global__ __launch_bounds__(256) void k_mlp(const float* __restrict__ x1,
    const float* __restrict__ W2, const float* __restrict__ b2,
    const float* __restrict__ W3, const float* __restrict__ b3,
    const float* __restrict__ W4, const float* __restrict__ b4,
    float* __restrict__ z) {
  __shared__ float lX[32 * 51];
  __shared__ float lW2[50 * 52];
  __shared__ float lW3[50 * 52];
  __shared__ float lW4[50 * 8];
  const int tid = threadIdx.x;
  const int row0 = blockIdx.x * 32;
  for (int idx = tid; idx < 2500; idx += 256) {
    int k = idx / 50, n = idx % 50;
    lW2[k * 52 + n] = W2[idx];
    lW3[k * 52 + n] = W3[idx];
  }
  for (int idx = tid; idx < 300; idx += 256) {
    int k = idx / 6, n = idx % 6;
    lW4[k * 8 + n] = W4[idx];
  }
  for (int idx = tid; idx < 1600; idx += 256) {
    int r = idx / 50, k = idx % 50;
    int gr = row0 + r;
    lX[r * 51 + k] = (gr < M_NODES) ? x1[gr * 50 + k] : 0.f;
  }
  __syncthreads();
  const int r = tid >> 3, cg = tid & 7;
  float x[50];
  #pragma unroll
  for (int k = 0; k < 50; ++k) x[k] = lX[r * 51 + k];

  for (int layer = 0; layer < 2; ++layer) {
    const float* lW = (layer == 0) ? lW2 : lW3;
    const float* bg = (layer == 0) ? b2 : b3;
    float acc[7];
    #pragma unroll
    for (int j = 0; j < 7; ++j) {
      int n = cg + 8 * j;
      acc[j] = (n < 50) ? bg[n] : 0.f;
    }
    #pragma unroll
    for (int k = 0; k < 50; ++k) {
      float xk = x[k];
      #pragma unroll
      for (int j = 0; j < 7; ++j) {
        int n = cg + 8 * j;
        if (n < 50) acc[j] = fmaf(xk, lW[k * 52 + n], acc[j]);
      }
    }
    __syncthreads();
    #pragma unroll
    for (int j = 0; j < 7; ++j) {
      int n = cg + 8 * j;
      if (n < 50) lX[r * 51 + n] = fmaxf(acc[j], 0.f);
    }
    __syncthreads();
    #pragma unroll
    for (int k = 0; k < 50; ++k) x[k] = lX[r * 51 + k];
  }
  if (cg < 6) {
    float accz = b4[cg];
    #pragma unroll
    for (int k = 0; k < 50; ++k) accz = fmaf(x[k], lW4[k * 8 + cg], accz);
    int gr = row0 + r;
    if (gr < M_NODES) z[gr * 6 + cg] = accz;
  }
}

// ============ CSR incidence build ============
__global__ void k_count(const int* __restrict__ sx, const int* __restrict__ sy,
                        int* __restrict__ cnt) {
  int e = blockIdx.x * 256 + threadIdx.x;
  if (e >= N_EDGES_C) return;
  atomicAdd(&cnt[sx[e]], 1);
  atomicAdd(&cnt[sy[e]], 1);
}

__global__ __launch_bounds__(1024) void k_scan(const int* __restrict__ cnt,
                                               int* __restrict__ off,
                                               int* __restrict__ cur) {
  __shared__ int sums[1024];
  int t = threadIdx.x;
  int base = t * 20;
  int local[20];
  int s = 0;
  #pragma unroll
  for (int j = 0; j < 20; ++j) {
    int idx = base + j;
    int v = (idx < M_NODES) ? cnt[idx] : 0;
    local[j] = s;
    s += v;
  }
  sums[t] = s;
  __syncthreads();
  for (int d = 1; d < 1024; d <<= 1) {
    int v = (t >= d) ? sums[t - d] : 0;
    __syncthreads();
    sums[t] += v;
    __syncthreads();
  }
  int excl = sums[t] - s;
  #pragma unroll
  for (int j = 0; j < 20; ++j) {
    int idx = base + j;
    if (idx < M_NODES) {
      int o = excl + local[j];
      off[idx] = o;
      cur[idx] = o;
    }
  }
  if (t == 1023) off[M_NODES] = sums[1023];
}

// packed entry: {partner<<1 | side, rel_bits}
__global__ void k_scatter(const int* __restrict__ sx, const int* __restrict__ sy,
                          const float* __restrict__ rel,
                          int* __restrict__ cur, int2* __restrict__ ent) {
  int e = blockIdx.x * 256 + threadIdx.x;
  if (e >= N_EDGES_C) return;
  int a = sx[e], b = sy[e];
  int rb = __float_as_int(rel[e]);
  int p = atomicAdd(&cur[a], 1);
  ent[p] = make_int2((b << 1), rb);       // node a is x-side (side 0)
  int q = atomicAdd(&cur[b], 1);
  ent[q] = make_int2((a << 1) | 1, rb);   // node b is y-side (side 1)
}

// ============ KENN gather + in-wave combine (+ optional softmax) — r12-proven ============
__global__ __launch_bounds__(256) void k_gather(const float* __restrict__ z,
    const int* __restrict__ off, const int2* __restrict__ ent,
    const float* __restrict__ cw, float* __restrict__ zn,
    float* __restrict__ out, int last) {
  int t = blockIdx.x * 256 + threadIdx.x;
  int s = t & 7;
  int n = t >> 3;
  int o0 = off[n];
  int deg = off[n + 1] - o0;
  int lo = o0 + ((deg * s) >> 3);
  int hi = o0 + ((deg * (s + 1)) >> 3);

  const float2* zr = (const float2*)(z + n * 6);
  float2 a0 = zr[0], a1 = zr[1], a2 = zr[2];
  float znv[6] = {a0.x, a0.y, a1.x, a1.y, a2.x, a2.y};
  float w[6];
  #pragma unroll
  for (int c = 0; c < 6; ++c) w[c] = cw[c];
  float en_neg[6], en_pos[6];
  #pragma unroll
  for (int c = 0; c < 6; ++c) {
    en_neg[c] = __expf(-znv[c]);
    en_pos[c] = __expf(znv[c]);
  }
  float dz[6] = {0.f, 0.f, 0.f, 0.f, 0.f, 0.f};

  for (int i = lo; i < hi; ++i) {
    int2 e2 = ent[i];
    int partner = e2.x >> 1;
    int side = e2.x & 1;
    float r = __int_as_float(e2.y);
    const float2* zp2 = (const float2*)(z + partner * 6);
    float2 p0 = zp2[0], p1 = zp2[1], p2 = zp2[2];
    float zpv[6] = {p0.x, p0.y, p1.x, p1.y, p2.x, p2.y};
    float e2v = __expf(-r);
    #pragma unroll
    for (int c = 0; c < 6; ++c) {
      float e0 = side ? __expf(-zpv[c]) : en_neg[c];
      float e1 = side ? en_pos[c] : __expf(zpv[c]);
      float inv = w[c] / (e0 + e1 + e2v);
      dz[c] += (side ? e1 : -e0) * inv;
    }
  }

  #pragma unroll
  for (int c = 0; c < 6; ++c) {
    float v = dz[c];
    v += __shfl_xor(v, 1, 8);
    v += __shfl_xor(v, 2, 8);
    v += __shfl_xor(v, 4, 8);
    dz[c] = v;
  }

  if (s == 0) {
    float v[6];
    #pragma unroll
    for (int c = 0; c < 6; ++c) v[c] = znv[c] + dz[c];
    if (!last) {
      float2* o2 = (float2*)(zn + n * 6);
      o2[0] = make_float2(v[0], v[1]);
      o2[1] = make_float2(v[2], v[3]);
      o2[2] = make_float2(v[4], v[5]);
    } else {
      float m = v[0];
      #pragma unroll
      for (int c = 1; c < 6; ++c) m = fmaxf(m, v[c]);
      float sum = 0.f, ev[6];
      #pragma unroll
      for (int c = 0; c < 6; ++c) { ev[c] = __expf(v[c] - m); sum += ev[c]; }
      float inv = 1.f / sum;
      float2* o2 = (float2*)(out + n * 6);
      o2[0] = make_float2(ev[0] * inv, ev[1] * inv);
      o2[1] = make_float2(ev[2] * inv, ev[3] * inv);
      o2[2] = make_float2(ev[4] * inv, ev[5] * inv);
    }
  }
}

extern "C" void kernel_launch(void* const* d_in, const int* in_sizes, int n_in,
                              void* d_out, int out_size, void* d_ws, size_t ws_size,
                              hipStream_t stream) {
  const float* A   = (const float*)d_in[0];
  const float* rel = (const float*)d_in[1];
  const int*   sx  = (const int*)d_in[2];
  const int*   sy  = (const int*)d_in[3];
  const float* W1  = (const float*)d_in[4];
  const float* b1  = (const float*)d_in[5];
  const float* W2  = (const float*)d_in[6];
  const float* b2  = (const float*)d_in[7];
  const float* W3  = (const float*)d_in[8];
  const float* b3  = (const float*)d_in[9];
  const float* W4  = (const float*)d_in[10];
  const float* b4  = (const float*)d_in[11];
  const float* cw  = (const float*)d_in[12];

  const int S = 8, KS = 512;    // 157x8 = 1256 blocks

  float* base = (float*)d_ws;
  float* part = base;                         // 8M floats (dead after k_epi; CSR aliases)
  float* x1   = base + 8000000;               // 1M
  float* zA   = base + 9000000;               // 120000
  float* zB   = base + 9120000;               // 120000
  unsigned short* Bph = (unsigned short*)(base + 9240000);   // 237568 ushorts
  unsigned short* Bpl = (unsigned short*)(base + 9360000);   // 237568 ushorts

  // CSR arrays alias the part region (dead after k_epi)
  int*  cnt  = (int*)base;                    // 20001
  int*  off  = (int*)base + 24576;            // 20001
  int*  cur  = (int*)base + 49152;            // 20001
  int2* ent  = (int2*)((int*)base + 73728);   // 1.28M int2 -> ends 2,633,728 ints

  k_packB<<<(NKB * 4 * 64 * 8 + 255) / 256, 256, 0, stream>>>(W1, Bph, Bpl);
  k_gemm1<<<dim3(157, S), 256, 0, stream>>>(A, Bph, Bpl, part, KS);
  k_epi<<<(M_NODES * NH + 255) / 256, 256, 0, stream>>>(part, b1, x1, S);
  k_mlp<<<(M_NODES + 31) / 32, 256, 0, stream>>>(x1, W2, b2, W3, b3, W4, b4, zA);

  hipMemsetAsync(cnt, 0, (M_NODES + 1) * sizeof(int), stream);
  k_count<<<(N_EDGES_C + 255) / 256, 256, 0, stream>>>(sx, sy, cnt);
  k_scan<<<1, 1024, 0, stream>>>(cnt, off, cur);
  k_scatter<<<(N_EDGES_C + 255) / 256, 256, 0, stream>>>(sx, sy, rel, cur, ent);

  float* zc = zA;
  float* zn = zB;
  for (int l = 0; l < 3; ++l) {
    k_gather<<<M_NODES * 8 / 256, 256, 0, stream>>>(
        zc, off, ent, cw + 6 * l, zn, (float*)d_out, (l == 2) ? 1 : 0);
    float* t = zc; zc = zn; zn = t;
  }
}